// Round 15
// baseline (149.031 us; speedup 1.0000x reference)
//
#include <hip/hip_runtime.h>
#include <hip/hip_bf16.h>

typedef __attribute__((ext_vector_type(8))) short bf16x8;
typedef __attribute__((ext_vector_type(4))) float f32x4;
typedef __attribute__((ext_vector_type(4))) unsigned int u32x4;
typedef __attribute__((ext_vector_type(2))) unsigned int u32x2;

#define B_SZ 4
#define C_SZ 256
#define N_SZ 4096
#define DK_SZ 32

// ws layout in bf16 elements
#define WQB_OFF 0
#define WKB_OFF 8192
#define WVB_OFF 16384
#define QB_OFF  81920
#define KB_OFF  606208
#define VB_OFF  1130496   // V tiled: [b][mblk=n/64][c][64]

__device__ __forceinline__ short f2bf(float f) {
    union { float f; unsigned int u; } v; v.f = f;
    unsigned int r = v.u + 0x7fffu + ((v.u >> 16) & 1u);
    return (short)(r >> 16);
}

__device__ __forceinline__ float asf(unsigned int u) {
    union { unsigned int u; float f; } v; v.u = u;
    return v.f;
}

__device__ __forceinline__ unsigned int cvt_pk_bf16(float lo, float hi) {
    unsigned int r;
    asm volatile("v_cvt_pk_bf16_f32 %0, %1, %2" : "=v"(r) : "v"(lo), "v"(hi));
    return r;
}

__device__ __forceinline__ f32x4 mfma16(bf16x8 a, bf16x8 b, f32x4 c) {
    return __builtin_amdgcn_mfma_f32_16x16x32_bf16(a, b, c, 0, 0, 0);
}

// XCD-affinity remap: grid 256, block i -> XCD i%8; batch b owns XCDs {2b,2b+1}.
__device__ __forceinline__ void remap_block(int i, int& b, int& n0) {
    b = (i & 7) >> 1;
    n0 = (((i >> 3) << 1) | (i & 1)) * 64;
}

// ---------------- weight conversion ----------------
__global__ __launch_bounds__(256) void k_convw(const float* __restrict__ Wq,
                                               const float* __restrict__ Wk,
                                               const float* __restrict__ Wv,
                                               short* __restrict__ ws) {
    int i = blockIdx.x * 256 + threadIdx.x;
    if (i < 8192) {
        ws[WQB_OFF + i] = f2bf(Wq[i]);
        ws[WKB_OFF + i] = f2bf(Wk[i]);
    }
    ws[WVB_OFF + i] = f2bf(Wv[i]);
}

// ---------------- projection: q, k as [b][n][32] bf16; v TILED [b][mblk][c][64] ----------------
__global__ __launch_bounds__(256) void k_prep(const float* __restrict__ x,
                                              const float* __restrict__ bq,
                                              const float* __restrict__ bk,
                                              const float* __restrict__ bv,
                                              short* __restrict__ ws) {
    __shared__ short xsT[64][264];
    __shared__ short vt_s[64][258];

    int b, n0;
    remap_block(blockIdx.x, b, n0);
    const int t = threadIdx.x;
    const float* xb = x + (size_t)b * C_SZ * N_SZ;

    {
        int c0 = t >> 4, n4 = (t & 15) * 4;
#pragma unroll
        for (int i = 0; i < 16; i++) {
            int c = c0 + 16 * i;
            float4 v = *(const float4*)(xb + (size_t)c * N_SZ + n0 + n4);
            xsT[n4 + 0][c] = f2bf(v.x);
            xsT[n4 + 1][c] = f2bf(v.y);
            xsT[n4 + 2][c] = f2bf(v.z);
            xsT[n4 + 3][c] = f2bf(v.w);
        }
    }
    __syncthreads();

    const int w = t >> 6, l = t & 63;
    const int lr = l & 15, lk = l >> 4;

    bf16x8 af[8];
#pragma unroll
    for (int kk = 0; kk < 8; kk++)
        af[kk] = *(const bf16x8*)(&xsT[w * 16 + lr][kk * 32 + lk * 8]);

#pragma unroll
    for (int qk = 0; qk < 2; qk++) {
        const short* wb = ws + (qk ? WKB_OFF : WQB_OFF);
        const float* bias = qk ? bk : bq;
        short* outp = ws + (qk ? KB_OFF : QB_OFF) + (size_t)b * N_SZ * DK_SZ;
#pragma unroll
        for (int cf = 0; cf < 2; cf++) {
            f32x4 acc = {0.f, 0.f, 0.f, 0.f};
#pragma unroll
            for (int kk = 0; kk < 8; kk++) {
                bf16x8 bfr = *(const bf16x8*)(wb + (cf * 16 + lr) * 256 + kk * 32 + lk * 8);
                acc = mfma16(af[kk], bfr, acc);
            }
            float bias_v = bias[cf * 16 + lr];
#pragma unroll
            for (int r = 0; r < 4; r++) {
                int row = w * 16 + lk * 4 + r;
                outp[(size_t)(n0 + row) * DK_SZ + cf * 16 + lr] = f2bf(acc[r] + bias_v);
            }
        }
    }

#pragma unroll
    for (int cf = 0; cf < 16; cf++) {
        f32x4 acc = {0.f, 0.f, 0.f, 0.f};
#pragma unroll
        for (int kk = 0; kk < 8; kk++) {
            bf16x8 bfr = *(const bf16x8*)(ws + WVB_OFF + (cf * 16 + lr) * 256 + kk * 32 + lk * 8);
            acc = mfma16(af[kk], bfr, acc);
        }
        float bias_v = bv[cf * 16 + lr];
#pragma unroll
        for (int r = 0; r < 4; r++) {
            vt_s[w * 16 + lk * 4 + r][cf * 16 + lr] = f2bf(acc[r] + bias_v);
        }
    }
    __syncthreads();
    {
        // tiled V write: [mblk = n0/64][c][64]
        short* vt = ws + VB_OFF + (size_t)b * C_SZ * N_SZ + (size_t)(n0 >> 6) * (C_SZ * 64);
        int nn = t & 63;
#pragma unroll
        for (int i = 0; i < 64; i++) {
            int c = (t >> 6) + 4 * i;
            vt[c * 64 + nn] = vt_s[nn][c];
        }
    }
}

// ---------------- fused attention (fat iters: 2 tiles/barrier, all-register prefetch) ----------------
// 512 thr = 8 waves, grid 256 (1 block/CU). SCOMP map: rg=w&3 (16 q-rows),
// ch=w>>2 (m-half). PV map: rg = 64-channel quarter, ch = m-half.
// 32 fat iterations, each processing tiles {2f, 2f+1} under ONE barrier:
//   [prefetch V(2f+2,2f+3) + K(2f+4,2f+5) into REGISTERS (plain loads,
//    compiler-placed vmcnt at use = ~1 fat-iter slack)]
//   [SCOMP(2f+2),(2f+3): mfma + exp -> p_lds ring slot (t&3)]
//   [ASTORE(2f),(2f+1): full-128B-line nt stores from p_lds]
//   [PV(2f),(2f+1): 32 mfma from V-regs x p_lds B-frags]
//   [lgkmcnt(0); s_barrier]   <- NO vmcnt drain: prefetches + stores ride.
// LDS: P ring [4][64][72] (36.9 KB) + rsum; epilogue reuses 70 KB.
__global__ __launch_bounds__(512, 1) void k_attn(const short* __restrict__ ws,
                                                 const float* __restrict__ x,
                                                 const float* __restrict__ gamma_p,
                                                 float* __restrict__ out) {
    __shared__ __align__(16) char smem[69888];
    short (*p_lds)[64][72] = (short(*)[64][72])smem;   // [4][64][72] = 36864 B
    float* rsum_s = (float*)(smem + 36864);            // [2][64]

    int b, n0;
    remap_block(blockIdx.x, b, n0);
    const int t = threadIdx.x, w = t >> 6, l = t & 63;
    const int rg = w & 3, ch = w >> 2;
    const int lr = l & 15, lk = l >> 4;

    const short* qb = ws + QB_OFF + (size_t)b * N_SZ * DK_SZ;
    const short* kb = ws + KB_OFF + (size_t)b * N_SZ * DK_SZ;
    const short* vb2 = ws + VB_OFF + (size_t)b * C_SZ * N_SZ;   // tiled [mblk][c][64]

    bf16x8 qf = *(const bf16x8*)(qb + (size_t)(n0 + rg * 16 + lr) * DK_SZ + lk * 8);

    // ---- pass 1: rowsum of exp(S) over m-half ch, barrier-free ----
    float rs = 0.f;
#pragma unroll 2
    for (int mt = 0; mt < 32; mt++) {
        int mb = ch * 2048 + mt * 64;
        bf16x8 kfa = *(const bf16x8*)(kb + (size_t)(mb + lr) * DK_SZ + lk * 8);
        bf16x8 kfb = *(const bf16x8*)(kb + (size_t)(mb + 16 + lr) * DK_SZ + lk * 8);
        bf16x8 kfc = *(const bf16x8*)(kb + (size_t)(mb + 32 + lr) * DK_SZ + lk * 8);
        bf16x8 kfd = *(const bf16x8*)(kb + (size_t)(mb + 48 + lr) * DK_SZ + lk * 8);
        f32x4 s0 = mfma16(kfa, qf, (f32x4){0.f, 0.f, 0.f, 0.f});
        f32x4 s1 = mfma16(kfb, qf, (f32x4){0.f, 0.f, 0.f, 0.f});
        f32x4 s2 = mfma16(kfc, qf, (f32x4){0.f, 0.f, 0.f, 0.f});
        f32x4 s3 = mfma16(kfd, qf, (f32x4){0.f, 0.f, 0.f, 0.f});
#pragma unroll
        for (int r = 0; r < 4; r++)
            rs += __expf(s0[r]) + __expf(s1[r]) + __expf(s2[r]) + __expf(s3[r]);
    }
    rs += __shfl_xor(rs, 16);
    rs += __shfl_xor(rs, 32);
    if (l < 16) rsum_s[ch * 64 + rg * 16 + l] = rs;
    __syncthreads();
    const float invp = 1.f / (rsum_s[rg * 16 + lr] + rsum_s[64 + rg * 16 + lr]);

    // ---- pass 2 ----
    float* attn_b = out + (size_t)B_SZ * C_SZ * N_SZ + (size_t)b * N_SZ * N_SZ;
    f32x4 O[4][4];   // O[cf][rgi]: c = rg*64+cf*16+4lk+r, n = rgi*16+lr (m-half partial)
#pragma unroll
    for (int cf = 0; cf < 4; cf++)
#pragma unroll
        for (int rgi = 0; rgi < 4; rgi++) O[cf][rgi] = (f32x4){0.f, 0.f, 0.f, 0.f};

    // PV B-frag byte offset within a p_lds slot: row rgi*16+lr, m = ch*32+lk*8
    const int boff = lr * 144 + ch * 64 + lk * 16;

#define VLOAD(tt, vr)                                                               \
    {                                                                               \
        const short* vt = vb2 + (size_t)(tt) * (C_SZ * 64);                         \
        _Pragma("unroll")                                                           \
        for (int cf = 0; cf < 4; cf++)                                              \
            vr[cf] = *(const bf16x8*)(vt + (rg * 64 + cf * 16 + lr) * 64            \
                                      + ch * 32 + lk * 8);                          \
    }

#define KLOAD(tt, k0, k1)                                                           \
    {                                                                               \
        const int mb = (tt) * 64 + ch * 32;                                         \
        k0 = *(const bf16x8*)(kb + (size_t)(mb + lr) * DK_SZ + lk * 8);             \
        k1 = *(const bf16x8*)(kb + (size_t)(mb + 16 + lr) * DK_SZ + lk * 8);        \
    }

    // SCOMP(tt): S = mfma(K,Q); e = exp*inv; cvt; P -> p_lds[(tt)&3]
#define SCOMP(tt, k0, k1)                                                           \
    {                                                                               \
        f32x4 s0 = mfma16(k0, qf, (f32x4){0.f, 0.f, 0.f, 0.f});                     \
        f32x4 s1 = mfma16(k1, qf, (f32x4){0.f, 0.f, 0.f, 0.f});                     \
        float e00 = __expf(s0[0]) * invp, e01 = __expf(s0[1]) * invp;               \
        float e02 = __expf(s0[2]) * invp, e03 = __expf(s0[3]) * invp;               \
        float e10 = __expf(s1[0]) * invp, e11 = __expf(s1[1]) * invp;               \
        float e12 = __expf(s1[2]) * invp, e13 = __expf(s1[3]) * invp;               \
        u32x2 pk0, pk1;                                                             \
        pk0[0] = cvt_pk_bf16(e00, e01); pk0[1] = cvt_pk_bf16(e02, e03);             \
        pk1[0] = cvt_pk_bf16(e10, e11); pk1[1] = cvt_pk_bf16(e12, e13);             \
        *(u32x2*)(&p_lds[(tt) & 3][rg * 16 + lr][ch * 32 + lk * 4]) = pk0;          \
        *(u32x2*)(&p_lds[(tt) & 3][rg * 16 + lr][ch * 32 + 16 + lk * 4]) = pk1;     \
    }

    // ASTORE(tt): full-128B-line nt stores; lane l of wave w -> row w*8+(l>>3)
#define ASTORE(tt)                                                                  \
    {                                                                               \
        const int arow = w * 8 + (l >> 3);                                          \
        const char* pr = (const char*)&p_lds[(tt) & 3][arow][0];                    \
        u32x2 u0 = *(const u32x2*)(pr + (l & 7) * 8);                               \
        u32x2 u1 = *(const u32x2*)(pr + 64 + (l & 7) * 8);                          \
        f32x4 f0, f1;                                                               \
        f0[0] = asf(u0[0] << 16); f0[1] = asf(u0[0] & 0xffff0000u);                 \
        f0[2] = asf(u0[1] << 16); f0[3] = asf(u0[1] & 0xffff0000u);                 \
        f1[0] = asf(u1[0] << 16); f1[1] = asf(u1[0] & 0xffff0000u);                 \
        f1[2] = asf(u1[1] << 16); f1[3] = asf(u1[1] & 0xffff0000u);                 \
        float* dst = attn_b + (size_t)(n0 + arow) * N_SZ + (tt) * 64 + (l & 7) * 4; \
        __builtin_nontemporal_store(f0, (f32x4*)dst);                               \
        __builtin_nontemporal_store(f1, (f32x4*)(dst + 32));                        \
    }

#define PVOP(tt, vr)                                                                \
    {                                                                               \
        const char* pbase = (const char*)&p_lds[(tt) & 3][0][0];                    \
        bf16x8 Bfr[4];                                                              \
        _Pragma("unroll")                                                           \
        for (int rgi = 0; rgi < 4; rgi++)                                           \
            Bfr[rgi] = *(const bf16x8*)(pbase + rgi * 2304 + boff);                 \
        _Pragma("unroll")                                                           \
        for (int cf = 0; cf < 4; cf++)                                              \
            _Pragma("unroll")                                                       \
            for (int rgi = 0; rgi < 4; rgi++)                                       \
                O[cf][rgi] = mfma16(vr[cf], Bfr[rgi], O[cf][rgi]);                  \
    }

#define FITER(f, CV0, CV1, CK00, CK01, CK10, CK11, NV0, NV1, NK00, NK01, NK10, NK11) \
    {                                                                               \
        if ((f) < 31) { VLOAD(2 * (f) + 2, NV0); VLOAD(2 * (f) + 3, NV1); }         \
        if ((f) < 30) { KLOAD(2 * (f) + 4, NK00, NK01); KLOAD(2 * (f) + 5, NK10, NK11); } \
        __builtin_amdgcn_sched_barrier(0);                                          \
        if ((f) < 31) { SCOMP(2 * (f) + 2, CK00, CK01); SCOMP(2 * (f) + 3, CK10, CK11); } \
        __builtin_amdgcn_sched_barrier(0);                                          \
        ASTORE(2 * (f)); ASTORE(2 * (f) + 1);                                       \
        PVOP(2 * (f), CV0); PVOP(2 * (f) + 1, CV1);                                 \
        asm volatile("s_waitcnt lgkmcnt(0)" ::: "memory");                          \
        __builtin_amdgcn_sched_barrier(0);                                          \
        __builtin_amdgcn_s_barrier();                                               \
        __builtin_amdgcn_sched_barrier(0);                                          \
    }

    bf16x8 vA0[4], vA1[4], vB0[4], vB1[4];
    bf16x8 kA00, kA01, kA10, kA11, kB00, kB01, kB10, kB11;

    // prologue: V{0,1}->A, K{2,3}->A; K{0,1}->B (temp) for SCOMP(0,1)
    VLOAD(0, vA0); VLOAD(1, vA1);
    KLOAD(2, kA00, kA01); KLOAD(3, kA10, kA11);
    KLOAD(0, kB00, kB01); KLOAD(1, kB10, kB11);
    __builtin_amdgcn_sched_barrier(0);
    SCOMP(0, kB00, kB01); SCOMP(1, kB10, kB11);
    asm volatile("s_waitcnt lgkmcnt(0)" ::: "memory");
    __builtin_amdgcn_s_barrier();
    __builtin_amdgcn_sched_barrier(0);

    for (int f = 0; f < 32; f += 2) {
        FITER(f, vA0, vA1, kA00, kA01, kA10, kA11, vB0, vB1, kB00, kB01, kB10, kB11);
        FITER(f + 1, vB0, vB1, kB00, kB01, kB10, kB11, vA0, vA1, kA00, kA01, kA10, kA11);
    }
#undef VLOAD
#undef KLOAD
#undef SCOMP
#undef ASTORE
#undef PVOP
#undef FITER

    // ---- epilogue: reduce ch-pairs through LDS, then out = gamma*O + x ----
    __syncthreads();
    float* o_red = (float*)smem;     // [4 n-grp][256 c][16 n], c-stride 17
    const int RSTRIDE = 4360;
    if (ch == 1) {
#pragma unroll
        for (int cf = 0; cf < 4; cf++)
#pragma unroll
            for (int rgi = 0; rgi < 4; rgi++)
#pragma unroll
                for (int r = 0; r < 4; r++)
                    o_red[rgi * RSTRIDE + (rg * 64 + cf * 16 + 4 * lk + r) * 17 + lr] = O[cf][rgi][r];
    }
    __syncthreads();
    if (ch == 0) {
#pragma unroll
        for (int cf = 0; cf < 4; cf++)
#pragma unroll
            for (int rgi = 0; rgi < 4; rgi++)
#pragma unroll
                for (int r = 0; r < 4; r++) {
                    int idx = rgi * RSTRIDE + (rg * 64 + cf * 16 + 4 * lk + r) * 17 + lr;
                    o_red[idx] += O[cf][rgi][r];
                }
    }
    __syncthreads();
    {
        const float g = gamma_p[0];
        const float* xb = x + (size_t)b * C_SZ * N_SZ;
        float* ob = out + (size_t)b * C_SZ * N_SZ;
        int nn = t & 63;
        int c0 = t >> 6;   // 0..7
        int rbase = (nn >> 4) * RSTRIDE + (nn & 15);
#pragma unroll
        for (int i = 0; i < 32; i++) {
            int c = c0 + 8 * i;
            size_t idx = (size_t)c * N_SZ + n0 + nn;
            ob[idx] = g * o_red[rbase + c * 17] + xb[idx];
        }
    }
}

extern "C" void kernel_launch(void* const* d_in, const int* in_sizes, int n_in,
                              void* d_out, int out_size, void* d_ws, size_t ws_size,
                              hipStream_t stream) {
    const float* x     = (const float*)d_in[0];
    const float* Wq    = (const float*)d_in[1];
    const float* bq    = (const float*)d_in[2];
    const float* Wk    = (const float*)d_in[3];
    const float* bk    = (const float*)d_in[4];
    const float* Wv    = (const float*)d_in[5];
    const float* bv    = (const float*)d_in[6];
    const float* gamma = (const float*)d_in[7];
    short* ws = (short*)d_ws;
    float* out = (float*)d_out;

    hipLaunchKernelGGL(k_convw, dim3(256), dim3(256), 0, stream, Wq, Wk, Wv, ws);
    hipLaunchKernelGGL(k_prep, dim3(256), dim3(256), 0, stream, x, bq, bk, bv, ws);
    hipLaunchKernelGGL(k_attn, dim3(256), dim3(512), 0, stream, ws, x, gamma, out);
}